// Round 9
// baseline (635.891 us; speedup 1.0000x reference)
//
#include <hip/hip_runtime.h>

#define D 512
#define H1 1024
#define NNODES 50000
#define NEDGES 400000
#define MPAD 50176   // 196 * 256
#define NEG_SLOPE 0.2f
#define SCAN_BLOCKS 196   // 196*256 = 50176 >= 50000

typedef __attribute__((ext_vector_type(8))) short bf16x8;
typedef __attribute__((ext_vector_type(8))) unsigned short u16x8;
typedef __attribute__((ext_vector_type(4))) float f32x4;

// packed operand layout for GEMM operands:
// addr(r, k) = ((r>>7)*(K>>3) + (k>>3))*1024 + (r&127)*8 + (k&7)
// -> an MFMA A-fragment load (16 lanes x 16B, rows consecutive) is 256B
//    contiguous per kq group; A streaming loads are fully coalesced.

__device__ __forceinline__ unsigned short f2bf(float f) {
  unsigned int u = __float_as_uint(f);
  unsigned int r = u + 0x7FFFu + ((u >> 16) & 1u);
  return (unsigned short)(r >> 16);
}
__device__ __forceinline__ float bf2f(unsigned short h) {
  return __uint_as_float((unsigned int)h << 16);
}

// key[j] = sum_i cond[i] * Wk[i][j],  Wk is (256, 2D) row-major
__global__ void key_kernel(const float* __restrict__ cond, const float* __restrict__ Wk,
                           float* __restrict__ key) {
  int j = blockIdx.x * blockDim.x + threadIdx.x;
  if (j >= 2 * D) return;
  float s = 0.f;
#pragma unroll 8
  for (int i = 0; i < 256; ++i) s += cond[i] * Wk[i * (2 * D) + j];
  key[j] = s;
}

// one wave per node: nki/nkj dots + emit xb = bf16(x) row-major.
__global__ void nodedot_kernel(const float* __restrict__ x, const float* __restrict__ key,
                               float* __restrict__ nki, float* __restrict__ nkj,
                               unsigned short* __restrict__ xb) {
  int wid = (blockIdx.x * blockDim.x + threadIdx.x) >> 6;
  int lane = threadIdx.x & 63;
  if (wid >= NNODES) return;
  const float4* xr = (const float4*)(x + (size_t)wid * D);
  float4 p0 = xr[2 * lane], p1 = xr[2 * lane + 1];
  const float4* kia = (const float4*)key;
  const float4* kja = (const float4*)(key + D);
  float4 q0 = kia[2 * lane], q1 = kia[2 * lane + 1];
  float4 r0 = kja[2 * lane], r1 = kja[2 * lane + 1];
  float a = p0.x * q0.x + p0.y * q0.y + p0.z * q0.z + p0.w * q0.w +
            p1.x * q1.x + p1.y * q1.y + p1.z * q1.z + p1.w * q1.w;
  float b = p0.x * r0.x + p0.y * r0.y + p0.z * r0.z + p0.w * r0.w +
            p1.x * r1.x + p1.y * r1.y + p1.z * r1.z + p1.w * r1.w;
  u16x8 h;
  h[0] = f2bf(p0.x); h[1] = f2bf(p0.y); h[2] = f2bf(p0.z); h[3] = f2bf(p0.w);
  h[4] = f2bf(p1.x); h[5] = f2bf(p1.y); h[6] = f2bf(p1.z); h[7] = f2bf(p1.w);
  *(u16x8*)(xb + (size_t)wid * D + 8 * lane) = h;
#pragma unroll
  for (int off = 32; off > 0; off >>= 1) {
    a += __shfl_xor(a, off);
    b += __shfl_xor(b, off);
  }
  if (lane == 0) { nki[wid] = a; nkj[wid] = b; }
}

// W1 (D,2D) -> W1t packed (R=H1, K=D) ; W2 (2D,D) -> W2t packed (R=D, K=H1)
__global__ void convw_kernel(const float* __restrict__ W1, const float* __restrict__ W2,
                             unsigned short* __restrict__ W1t, unsigned short* __restrict__ W2t) {
  int idx = blockIdx.x * blockDim.x + threadIdx.x;
  if (idx >= D * H1) return;
  {
    int k = idx / H1, n = idx % H1;
    size_t a = (((size_t)(n >> 7) * (D >> 3) + (k >> 3)) << 10) + ((n & 127) << 3) + (k & 7);
    W1t[a] = f2bf(W1[idx]);
  }
  {
    int k = idx / D, n = idx % D;
    size_t a = (((size_t)(n >> 7) * (H1 >> 3) + (k >> 3)) << 10) + ((n & 127) << 3) + (k & 7);
    W2t[a] = f2bf(W2[idx]);
  }
}

// ---- CSR build ----
__global__ void zero_deg_kernel(int* __restrict__ deg) {
  int i = blockIdx.x * blockDim.x + threadIdx.x;
  if (i < NNODES) deg[i] = 0;
}

__global__ void hist_kernel(const int* __restrict__ row, int* __restrict__ deg) {
  int e = blockIdx.x * blockDim.x + threadIdx.x;
  if (e < NEDGES) atomicAdd(&deg[row[e]], 1);
}

__global__ void scan1_kernel(const int* __restrict__ deg, int* __restrict__ rowptr,
                             int* __restrict__ blktot) {
  __shared__ int s[256];
  int tid = threadIdx.x;
  int i = blockIdx.x * 256 + tid;
  int v = (i < NNODES) ? deg[i] : 0;
  s[tid] = v;
  __syncthreads();
#pragma unroll
  for (int off = 1; off < 256; off <<= 1) {
    int t = (tid >= off) ? s[tid - off] : 0;
    __syncthreads();
    s[tid] += t;
    __syncthreads();
  }
  if (i < NNODES) rowptr[i] = s[tid] - v;
  if (tid == 255) blktot[blockIdx.x] = s[255];
}

__global__ void scan2_kernel(int* __restrict__ blktot, int* __restrict__ blkoff) {
  __shared__ int s[256];
  int tid = threadIdx.x;
  int v = (tid < SCAN_BLOCKS) ? blktot[tid] : 0;
  s[tid] = v;
  __syncthreads();
#pragma unroll
  for (int off = 1; off < 256; off <<= 1) {
    int t = (tid >= off) ? s[tid - off] : 0;
    __syncthreads();
    s[tid] += t;
    __syncthreads();
  }
  if (tid < SCAN_BLOCKS) blkoff[tid] = s[tid] - v;
}

__global__ void scan3_kernel(int* __restrict__ rowptr, const int* __restrict__ blkoff,
                             int* __restrict__ cursor) {
  int i = blockIdx.x * blockDim.x + threadIdx.x;
  if (i < NNODES) {
    int v = rowptr[i] + blkoff[blockIdx.x];
    rowptr[i] = v;
    cursor[i] = v;
  }
  if (i == 0) rowptr[NNODES] = NEDGES;
}

// per edge: alpha = sigmoid(leaky(nki[col]+nkj[row])); place (col,alpha) into CSR slot
__global__ void fill_kernel(const int* __restrict__ row, const int* __restrict__ col,
                            const float* __restrict__ nki, const float* __restrict__ nkj,
                            int* __restrict__ cursor, int* __restrict__ scol,
                            float* __restrict__ salpha) {
  int e = blockIdx.x * blockDim.x + threadIdx.x;
  if (e >= NEDGES) return;
  int r = row[e], c = col[e];
  float a = nki[c] + nkj[r];
  a = (a >= 0.f) ? a : NEG_SLOPE * a;
  float al = 1.f / (1.f + expf(-a));
  int pos = atomicAdd(&cursor[r], 1);
  scol[pos] = c;
  salpha[pos] = al;
}

// one wave per node: Pb[n] = bf16(xb[n] + sum_e alpha_e * xb[scol[e]]), packed out.
__global__ __launch_bounds__(256) void agg_kernel(
    const unsigned short* __restrict__ xb, const int* __restrict__ rowptr,
    const int* __restrict__ scol, const float* __restrict__ salpha,
    unsigned short* __restrict__ Pb) {
  int n = (blockIdx.x * blockDim.x + threadIdx.x) >> 6;
  int lane = threadIdx.x & 63;
  if (n >= NNODES) return;
  int beg = rowptr[n], end = rowptr[n + 1];
  u16x8 self = *(const u16x8*)(xb + (size_t)n * D + 8 * lane);
  float sa[8], sb[8];
#pragma unroll
  for (int q = 0; q < 8; ++q) { sa[q] = bf2f(self[q]); sb[q] = 0.f; }
  int e = beg;
  for (; e + 1 < end; e += 2) {
    int c0 = scol[e], c1 = scol[e + 1];
    float al0 = salpha[e], al1 = salpha[e + 1];
    u16x8 w0 = *(const u16x8*)(xb + (size_t)c0 * D + 8 * lane);
    u16x8 w1 = *(const u16x8*)(xb + (size_t)c1 * D + 8 * lane);
#pragma unroll
    for (int q = 0; q < 8; ++q) {
      sa[q] += al0 * bf2f(w0[q]);
      sb[q] += al1 * bf2f(w1[q]);
    }
  }
  if (e < end) {
    int c0 = scol[e];
    float al0 = salpha[e];
    u16x8 w0 = *(const u16x8*)(xb + (size_t)c0 * D + 8 * lane);
#pragma unroll
    for (int q = 0; q < 8; ++q) sa[q] += al0 * bf2f(w0[q]);
  }
  u16x8 h;
#pragma unroll
  for (int q = 0; q < 8; ++q) h[q] = f2bf(sa[q] + sb[q]);
  *(u16x8*)(Pb + (((size_t)(n >> 7) * (D >> 3) + lane) << 10) + ((n & 127) << 3)) = h;
}

// ---- B-resident streaming GEMM (flat-GEMM style for tall-skinny M x small K) ----
// C = act(A @ Bt^T + bias). A, Bt PACKED. Block owns an n-column of NBLK cols:
// stages its FULL B panel (NBLK x K x 2B = 128 KB) into LDS once (XOR-swizzled,
// conflict-free ds_read_b128), then loops m-tiles (256 rows) grid-stride with NO
// barriers: per k32-step 4 contiguous A dwordx4 loads + 2 LDS B reads + 8 MFMA,
// 2-deep pipeline that rolls ACROSS m-tile boundaries (never drains).
// Waves: NWM=4 x NWN (G1: 4 -> 1024thr, G2: 2 -> 512thr); wave out = 64 x 32.
template <int K, int NWN, bool RELU_OUT_BF16>
__global__ __launch_bounds__(NWN * 256) void gemm_bres(
    const unsigned short* __restrict__ Ag, const unsigned short* __restrict__ Bt,
    const float* __restrict__ bias, void* __restrict__ Cptr, int M_valid, int N) {
  constexpr int NBLK = NWN * 32;
  constexpr int KC = K >> 3;      // 8-elem k-chunks
  constexpr int NSTEP = K >> 5;   // k32 steps (16 or 32)
  constexpr int THREADS = NWN * 256;
  constexpr int NGRAN = NBLK * KC;      // 16B granules in B panel (8192)
  constexpr int NTILES = MPAD / 256;    // 196
  __shared__ unsigned short Bs[NBLK * K];  // 128 KB

  const int bx = blockIdx.x;
  const int by = blockIdx.y;
  const int tid = threadIdx.x;
  const int lane = tid & 63;
  const int wave = tid >> 6;
  const int wm = (wave / NWN) * 64;   // 0..192
  const int wn = (wave % NWN) * 32;
  const int fr = lane & 15;
  const int kq = lane >> 4;           // 0..3

  // ---- stage B panel into LDS once (coalesced global, swizzled cols) ----
  for (int g = tid; g < NGRAN; g += THREADS) {
    const int col = g % NBLK, kc = g / NBLK;
    const int cg = bx * NBLK + col;
    u16x8 v = *(const u16x8*)(Bt + (((size_t)(cg >> 7) * KC + kc) << 10) + ((cg & 127) << 3));
    const int scol = col ^ ((col >> 3) & 3) ^ ((kc & 1) << 2);
    *(u16x8*)&Bs[(kc * NBLK + scol) * 8] = v;
  }
  __syncthreads();  // the only barrier

  // wave-constant part of the A fragment address
  const unsigned short* Aw = Ag + ((wm & 127) + fr) * 8 + kq * 1024;
  const int mrb = wm >> 7;  // which 128-row block within the 256-row tile

  f32x4 acc[4][2];
#pragma unroll
  for (int i = 0; i < 4; ++i)
#pragma unroll
    for (int j = 0; j < 2; ++j)
#pragma unroll
      for (int r = 0; r < 4; ++r) acc[i][j][r] = 0.f;

  bf16x8 a0[4], a1[4], bv0[2], bv1[2];

#define LOADA(AV, MT, T)                                                              \
  {                                                                                   \
    const unsigned short* ap_ =                                                       \
        Aw + (((size_t)((MT) * 2 + mrb) * KC) << 10) + (T) * 4096;                    \
    _Pragma("unroll") for (int i = 0; i < 4; ++i)                                     \
        AV[i] = *(const bf16x8*)(ap_ + i * 128);                                      \
  }
#define LOADB(BV, T)                                                                  \
  {                                                                                   \
    _Pragma("unroll") for (int j = 0; j < 2; ++j) {                                   \
      const int col_ = wn + j * 16 + fr;                                              \
      const int kc_ = (T) * 4 + kq;                                                   \
      const int scol_ = col_ ^ ((col_ >> 3) & 3) ^ ((kc_ & 1) << 2);                  \
      BV[j] = *(const bf16x8*)&Bs[(kc_ * NBLK + scol_) * 8];                          \
    }                                                                                 \
  }
#define MFMASET(AV, BV)                                                               \
  _Pragma("unroll") for (int i = 0; i < 4; ++i)                                       \
      _Pragma("unroll") for (int j = 0; j < 2; ++j)                                   \
          acc[i][j] = __builtin_amdgcn_mfma_f32_16x16x32_bf16(AV[i], BV[j],           \
                                                              acc[i][j], 0, 0, 0);

  LOADA(a0, by, 0) LOADB(bv0, 0)
  for (int mt = by; mt < NTILES; mt += 32) {
    const int mtn = (mt + 32 < NTILES) ? mt + 32 : mt;
#pragma unroll
    for (int t = 0; t < NSTEP - 2; t += 2) {
      LOADA(a1, mt, t + 1) LOADB(bv1, t + 1)
      MFMASET(a0, bv0)
      LOADA(a0, mt, t + 2) LOADB(bv0, t + 2)
      MFMASET(a1, bv1)
    }
    LOADA(a1, mt, NSTEP - 1) LOADB(bv1, NSTEP - 1)
    MFMASET(a0, bv0)
    LOADA(a0, mtn, 0) LOADB(bv0, 0)   // next tile's first set: pipeline rolls on
    MFMASET(a1, bv1)

    // epilogue for tile mt; C/D layout col = lane&15, row = (lane>>4)*4 + reg
    const int rg = kq * 4;
#pragma unroll
    for (int j = 0; j < 2; ++j) {
      const int gn = bx * NBLK + wn + j * 16 + fr;
      const float bvl = bias[gn];
#pragma unroll
      for (int i = 0; i < 4; ++i) {
#pragma unroll
        for (int r = 0; r < 4; ++r) {
          const int lrow = wm + i * 16 + rg + r;
          const int gm = mt * 256 + lrow;
          float v = acc[i][j][r] + bvl;
          if constexpr (RELU_OUT_BF16) {
            v = fmaxf(v, 0.f);
            size_t aoff = (((size_t)(gm >> 7) * (N >> 3) + (gn >> 3)) << 10) +
                          ((gm & 127) << 3) + (gn & 7);
            ((unsigned short*)Cptr)[aoff] = f2bf(v);
          } else {
            if (gm < M_valid) ((float*)Cptr)[(size_t)gm * N + gn] = v;
          }
          acc[i][j][r] = 0.f;
        }
      }
    }
  }
#undef LOADA
#undef LOADB
#undef MFMASET
}

extern "C" void kernel_launch(void* const* d_in, const int* in_sizes, int n_in,
                              void* d_out, int out_size, void* d_ws, size_t ws_size,
                              hipStream_t stream) {
  const float* x    = (const float*)d_in[0];
  const int*   ei   = (const int*)d_in[1];
  const float* cond = (const float*)d_in[2];
  const float* Wk   = (const float*)d_in[3];
  const float* W1   = (const float*)d_in[4];
  const float* b1   = (const float*)d_in[5];
  const float* W2   = (const float*)d_in[6];
  const float* b2   = (const float*)d_in[7];
  float* out = (float*)d_out;

  char* ws = (char*)d_ws;
  size_t off = 0;
  auto alloc = [&](size_t b) { size_t p = off; off += (b + 255) & ~(size_t)255; return p; };
  float* key = (float*)(ws + alloc(2 * D * sizeof(float)));
  float* nki = (float*)(ws + alloc(NNODES * sizeof(float)));
  float* nkj = (float*)(ws + alloc(NNODES * sizeof(float)));
  int* deg    = (int*)(ws + alloc(NNODES * sizeof(int)));
  int* rowptr = (int*)(ws + alloc((NNODES + 1) * sizeof(int)));
  int* cursor = (int*)(ws + alloc(NNODES * sizeof(int)));
  int* blktot = (int*)(ws + alloc(SCAN_BLOCKS * sizeof(int)));
  int* blkoff = (int*)(ws + alloc(SCAN_BLOCKS * sizeof(int)));
  int* scol      = (int*)(ws + alloc(NEDGES * sizeof(int)));
  float* salpha  = (float*)(ws + alloc(NEDGES * sizeof(float)));
  unsigned short* xb  = (unsigned short*)(ws + alloc((size_t)NNODES * D * 2));  // bf16 x, row-major
  unsigned short* W1t = (unsigned short*)(ws + alloc((size_t)H1 * D * 2));      // packed (R=H1,K=D)
  unsigned short* W2t = (unsigned short*)(ws + alloc((size_t)D * H1 * 2));      // packed (R=D,K=H1)
  unsigned short* Pb  = (unsigned short*)(ws + alloc((size_t)MPAD * D * 2));    // packed (R=MPAD,K=D)
  unsigned short* Hb  = (unsigned short*)(ws + alloc((size_t)MPAD * H1 * 2));   // packed (R=MPAD,K=H1)

  const int* row = ei;
  const int* col = ei + NEDGES;

  key_kernel<<<dim3((2 * D + 255) / 256), dim3(256), 0, stream>>>(cond, Wk, key);
  nodedot_kernel<<<dim3(NNODES * 64 / 256), dim3(256), 0, stream>>>(x, key, nki, nkj, xb);
  convw_kernel<<<dim3(D * H1 / 256), dim3(256), 0, stream>>>(W1, W2, W1t, W2t);

  // CSR build
  zero_deg_kernel<<<dim3(SCAN_BLOCKS), dim3(256), 0, stream>>>(deg);
  hist_kernel<<<dim3((NEDGES + 255) / 256), dim3(256), 0, stream>>>(row, deg);
  scan1_kernel<<<dim3(SCAN_BLOCKS), dim3(256), 0, stream>>>(deg, rowptr, blktot);
  scan2_kernel<<<dim3(1), dim3(256), 0, stream>>>(blktot, blkoff);
  scan3_kernel<<<dim3(SCAN_BLOCKS), dim3(256), 0, stream>>>(rowptr, blkoff, cursor);
  fill_kernel<<<dim3((NEDGES + 255) / 256), dim3(256), 0, stream>>>(row, col, nki, nkj,
                                                                    cursor, scol, salpha);
  // aggregate: Pb = bf16(xb + segment_sum(alpha * xb[col])), packed
  agg_kernel<<<dim3(NNODES * 64 / 256 + 1), dim3(256), 0, stream>>>(xb, rowptr, scol, salpha, Pb);

  // GEMM1: Hb = relu(Pb @ W1 + b1)  [M=50176, K=512, N=1024]  8 cols x 32, 1024 thr
  gemm_bres<512, 4, true><<<dim3(8, 32), dim3(1024), 0, stream>>>(
      Pb, W1t, b1, Hb, NNODES, H1);
  // GEMM2: out = Hb @ W2 + b2       [M=50176, K=1024, N=512]  8 cols x 32, 512 thr
  gemm_bres<1024, 2, false><<<dim3(8, 32), dim3(512), 0, stream>>>(
      Hb, W2t, b2, out, NNODES, D);
}

// Round 10
// 397.529 us; speedup vs baseline: 1.5996x; 1.5996x over previous
//
#include <hip/hip_runtime.h>

#define D 512
#define H1 1024
#define NNODES 50000
#define NEDGES 400000
#define MPAD 50176   // 196 * 256
#define NEG_SLOPE 0.2f
#define SCAN_BLOCKS 196   // 196*256 = 50176 >= 50000

typedef __attribute__((ext_vector_type(8))) short bf16x8;
typedef __attribute__((ext_vector_type(8))) unsigned short u16x8;
typedef __attribute__((ext_vector_type(4))) float f32x4;

// packed operand layout: addr(r,k) = ((r>>7)*(K>>3) + (k>>3))*1024 + (r&127)*8 + (k&7)
// -> one half-tile (128 rows x 64 k) = 8 contiguous 1KB chunks; a wave's
//    global_load_lds segment is a single 1KB burst; LDS image linear.

__device__ __forceinline__ unsigned short f2bf(float f) {
  unsigned int u = __float_as_uint(f);
  unsigned int r = u + 0x7FFFu + ((u >> 16) & 1u);
  return (unsigned short)(r >> 16);
}
__device__ __forceinline__ float bf2f(unsigned short h) {
  return __uint_as_float((unsigned int)h << 16);
}

__device__ __forceinline__ void gl_lds16(const void* g, void* l) {
  __builtin_amdgcn_global_load_lds(
      (const __attribute__((address_space(1))) void*)g,
      (__attribute__((address_space(3))) void*)l, 16, 0, 0);
}

// key[j] = sum_i cond[i] * Wk[i][j]
__global__ void key_kernel(const float* __restrict__ cond, const float* __restrict__ Wk,
                           float* __restrict__ key) {
  int j = blockIdx.x * blockDim.x + threadIdx.x;
  if (j >= 2 * D) return;
  float s = 0.f;
#pragma unroll 8
  for (int i = 0; i < 256; ++i) s += cond[i] * Wk[i * (2 * D) + j];
  key[j] = s;
}

// one wave per node: nki/nkj dots + emit xb = bf16(x) row-major.
__global__ void nodedot_kernel(const float* __restrict__ x, const float* __restrict__ key,
                               float* __restrict__ nki, float* __restrict__ nkj,
                               unsigned short* __restrict__ xb) {
  int wid = (blockIdx.x * blockDim.x + threadIdx.x) >> 6;
  int lane = threadIdx.x & 63;
  if (wid >= NNODES) return;
  const float4* xr = (const float4*)(x + (size_t)wid * D);
  float4 p0 = xr[2 * lane], p1 = xr[2 * lane + 1];
  const float4* kia = (const float4*)key;
  const float4* kja = (const float4*)(key + D);
  float4 q0 = kia[2 * lane], q1 = kia[2 * lane + 1];
  float4 r0 = kja[2 * lane], r1 = kja[2 * lane + 1];
  float a = p0.x * q0.x + p0.y * q0.y + p0.z * q0.z + p0.w * q0.w +
            p1.x * q1.x + p1.y * q1.y + p1.z * q1.z + p1.w * q1.w;
  float b = p0.x * r0.x + p0.y * r0.y + p0.z * r0.z + p0.w * r0.w +
            p1.x * r1.x + p1.y * r1.y + p1.z * r1.z + p1.w * r1.w;
  u16x8 h;
  h[0] = f2bf(p0.x); h[1] = f2bf(p0.y); h[2] = f2bf(p0.z); h[3] = f2bf(p0.w);
  h[4] = f2bf(p1.x); h[5] = f2bf(p1.y); h[6] = f2bf(p1.z); h[7] = f2bf(p1.w);
  *(u16x8*)(xb + (size_t)wid * D + 8 * lane) = h;
#pragma unroll
  for (int off = 32; off > 0; off >>= 1) {
    a += __shfl_xor(a, off);
    b += __shfl_xor(b, off);
  }
  if (lane == 0) { nki[wid] = a; nkj[wid] = b; }
}

// W1 (D,2D) -> W1t packed (R=H1, K=D) ; W2 (2D,D) -> W2t packed (R=D, K=H1)
__global__ void convw_kernel(const float* __restrict__ W1, const float* __restrict__ W2,
                             unsigned short* __restrict__ W1t, unsigned short* __restrict__ W2t) {
  int idx = blockIdx.x * blockDim.x + threadIdx.x;
  if (idx >= D * H1) return;
  {
    int k = idx / H1, n = idx % H1;
    size_t a = (((size_t)(n >> 7) * (D >> 3) + (k >> 3)) << 10) + ((n & 127) << 3) + (k & 7);
    W1t[a] = f2bf(W1[idx]);
  }
  {
    int k = idx / D, n = idx % D;
    size_t a = (((size_t)(n >> 7) * (H1 >> 3) + (k >> 3)) << 10) + ((n & 127) << 3) + (k & 7);
    W2t[a] = f2bf(W2[idx]);
  }
}

// ---- CSR build ----
__global__ void zero_deg_kernel(int* __restrict__ deg) {
  int i = blockIdx.x * blockDim.x + threadIdx.x;
  if (i < NNODES) deg[i] = 0;
}

__global__ void hist_kernel(const int* __restrict__ row, int* __restrict__ deg) {
  int e = blockIdx.x * blockDim.x + threadIdx.x;
  if (e < NEDGES) atomicAdd(&deg[row[e]], 1);
}

__global__ void scan1_kernel(const int* __restrict__ deg, int* __restrict__ rowptr,
                             int* __restrict__ blktot) {
  __shared__ int s[256];
  int tid = threadIdx.x;
  int i = blockIdx.x * 256 + tid;
  int v = (i < NNODES) ? deg[i] : 0;
  s[tid] = v;
  __syncthreads();
#pragma unroll
  for (int off = 1; off < 256; off <<= 1) {
    int t = (tid >= off) ? s[tid - off] : 0;
    __syncthreads();
    s[tid] += t;
    __syncthreads();
  }
  if (i < NNODES) rowptr[i] = s[tid] - v;
  if (tid == 255) blktot[blockIdx.x] = s[255];
}

__global__ void scan2_kernel(int* __restrict__ blktot, int* __restrict__ blkoff) {
  __shared__ int s[256];
  int tid = threadIdx.x;
  int v = (tid < SCAN_BLOCKS) ? blktot[tid] : 0;
  s[tid] = v;
  __syncthreads();
#pragma unroll
  for (int off = 1; off < 256; off <<= 1) {
    int t = (tid >= off) ? s[tid - off] : 0;
    __syncthreads();
    s[tid] += t;
    __syncthreads();
  }
  if (tid < SCAN_BLOCKS) blkoff[tid] = s[tid] - v;
}

__global__ void scan3_kernel(int* __restrict__ rowptr, const int* __restrict__ blkoff,
                             int* __restrict__ cursor) {
  int i = blockIdx.x * blockDim.x + threadIdx.x;
  if (i < NNODES) {
    int v = rowptr[i] + blkoff[blockIdx.x];
    rowptr[i] = v;
    cursor[i] = v;
  }
  if (i == 0) rowptr[NNODES] = NEDGES;
}

// per edge: alpha = sigmoid(leaky(nki[col]+nkj[row])); place (col,alpha) into CSR slot
__global__ void fill_kernel(const int* __restrict__ row, const int* __restrict__ col,
                            const float* __restrict__ nki, const float* __restrict__ nkj,
                            int* __restrict__ cursor, int* __restrict__ scol,
                            float* __restrict__ salpha) {
  int e = blockIdx.x * blockDim.x + threadIdx.x;
  if (e >= NEDGES) return;
  int r = row[e], c = col[e];
  float a = nki[c] + nkj[r];
  a = (a >= 0.f) ? a : NEG_SLOPE * a;
  float al = 1.f / (1.f + expf(-a));
  int pos = atomicAdd(&cursor[r], 1);
  scol[pos] = c;
  salpha[pos] = al;
}

// one wave per node: Pb[n] = bf16(xb[n] + sum_e alpha_e * xb[scol[e]]), packed out.
__global__ __launch_bounds__(256) void agg_kernel(
    const unsigned short* __restrict__ xb, const int* __restrict__ rowptr,
    const int* __restrict__ scol, const float* __restrict__ salpha,
    unsigned short* __restrict__ Pb) {
  int n = (blockIdx.x * blockDim.x + threadIdx.x) >> 6;
  int lane = threadIdx.x & 63;
  if (n >= NNODES) return;
  int beg = rowptr[n], end = rowptr[n + 1];
  u16x8 self = *(const u16x8*)(xb + (size_t)n * D + 8 * lane);
  float sa[8], sb[8];
#pragma unroll
  for (int q = 0; q < 8; ++q) { sa[q] = bf2f(self[q]); sb[q] = 0.f; }
  int e = beg;
  for (; e + 1 < end; e += 2) {
    int c0 = scol[e], c1 = scol[e + 1];
    float al0 = salpha[e], al1 = salpha[e + 1];
    u16x8 w0 = *(const u16x8*)(xb + (size_t)c0 * D + 8 * lane);
    u16x8 w1 = *(const u16x8*)(xb + (size_t)c1 * D + 8 * lane);
#pragma unroll
    for (int q = 0; q < 8; ++q) {
      sa[q] += al0 * bf2f(w0[q]);
      sb[q] += al1 * bf2f(w1[q]);
    }
  }
  if (e < end) {
    int c0 = scol[e];
    float al0 = salpha[e];
    u16x8 w0 = *(const u16x8*)(xb + (size_t)c0 * D + 8 * lane);
#pragma unroll
    for (int q = 0; q < 8; ++q) sa[q] += al0 * bf2f(w0[q]);
  }
  u16x8 h;
#pragma unroll
  for (int q = 0; q < 8; ++q) h[q] = f2bf(sa[q] + sb[q]);
  *(u16x8*)(Pb + (((size_t)(n >> 7) * (D >> 3) + lane) << 10) + ((n & 127) << 3)) = h;
}

// ---- m201-faithful 8-phase 256x256 GEMM on packed operands ----
// 8 waves (2M x 4N), wave out 128x64, BK=64, dbuf LDS 128KB.
// Iteration = 2 K-tiles (even->buf0, odd->buf1), 8 phases; phase = one C-quadrant
// (rh,ch) x K=64: {ds_reads 12/4/8/0, stage 1 half-tile, lgkmcnt(0), setprio(1),
// 16 MFMA, setprio(0), s_barrier}. vmcnt(6) only at phases 0 and 4.
// Stage slots (iteration i, tiles t=2i,t+1): p0:A0(t+1) p1:A1(t+1) p2:B0(t+2)
// p3:B1(t+2) p4:A0(t+2) p5:A1(t+2) p6:B0(t+3) p7:B1(t+3).  Safety: B(buf) fully
// read after its c1 phase (p1/p5); A(buf) after its r1 phase (p2/p6); every stage
// slot is after the corresponding end barrier.  Ledger (2 loads/half-tile):
// before p0, loads after tile t's last = B(t+1)x2 + A0(t+1) = 6 -> vmcnt(6);
// before p4, after tile t+1's last = B0,B1(t+2)+A0(t+2) = 6 (or 0 at tail).
template <int K, bool RELU_OUT_BF16>
__global__ __launch_bounds__(512, 2) void gemm8p(
    const unsigned short* __restrict__ Ag, const unsigned short* __restrict__ Bt,
    const float* __restrict__ bias, void* __restrict__ Cptr, int M_valid, int N) {
  constexpr int KC = K >> 3;
  constexpr int NT = K >> 6;  // K-tiles (8 or 16)
  __shared__ unsigned short As[2 * 2 * 8 * 1024];  // [buf][h][kc][row128][8] 64KB
  __shared__ unsigned short Bs[2 * 2 * 8 * 1024];

  const int G = gridDim.x * gridDim.y;
  const int orig = blockIdx.y * gridDim.x + blockIdx.x;
  const int wg = (orig & 7) * (G >> 3) + (orig >> 3);
  const int bx = wg % gridDim.x;
  const int by = wg / gridDim.x;

  const int tid = threadIdx.x;
  const int lane = tid & 63;
  const int wave = tid >> 6;
  const int wr = wave >> 2;          // M half (128 rows)
  const int wc = wave & 3;           // N quarter (64 cols)
  const int fr = lane & 15;
  const int kq = lane >> 4;          // 0..3
  const int bh = wc >> 1;            // B half-tile of this wave
  const int bc0 = (wc & 1) * 64;     // col base within B half

  f32x4 acc[8][4];
#pragma unroll
  for (int m = 0; m < 8; ++m)
#pragma unroll
    for (int n = 0; n < 4; ++n)
#pragma unroll
      for (int r = 0; r < 4; ++r) acc[m][n][r] = 0.f;

  bf16x8 aR[2][4];      // (kstep, i) for current (buf, rh)
  bf16x8 bC[2][2][2];   // (ch, kstep, j)

  // stage one half-tile (128 rows x 64 k): 2 gl_lds per thread, 1KB bursts
  auto stage = [&](const unsigned short* __restrict__ Gp, int bcoord, int buf, int h,
                   int t, unsigned short* Ls) {
#pragma unroll
    for (int L = 0; L < 2; ++L) {
      const int g = L * 512 + tid;
      const int kc = g >> 7, rw = g & 127;
      gl_lds16(Gp + (((size_t)(bcoord * 2 + h) * KC + t * 8 + kc) << 10) + rw * 8,
               Ls + (((buf * 2 + h) * 8 + kc) << 10) + rw * 8);
    }
  };
  auto dsA = [&](int buf, int rh) {
#pragma unroll
    for (int ks = 0; ks < 2; ++ks)
#pragma unroll
      for (int i = 0; i < 4; ++i)
        aR[ks][i] = *(const bf16x8*)&As[(((buf * 2 + wr) * 8 + ks * 4 + kq) << 10) +
                                        (rh * 64 + i * 16 + fr) * 8];
  };
  auto dsB = [&](int buf, int ch) {
#pragma unroll
    for (int ks = 0; ks < 2; ++ks)
#pragma unroll
      for (int j = 0; j < 2; ++j)
        bC[ch][ks][j] = *(const bf16x8*)&Bs[(((buf * 2 + bh) * 8 + ks * 4 + kq) << 10) +
                                            (bc0 + ch * 32 + j * 16 + fr) * 8];
  };
  auto mfma16 = [&](int rh, int ch) {
#pragma unroll
    for (int ks = 0; ks < 2; ++ks)
#pragma unroll
      for (int i = 0; i < 4; ++i)
#pragma unroll
        for (int j = 0; j < 2; ++j)
          acc[rh * 4 + i][ch * 2 + j] = __builtin_amdgcn_mfma_f32_16x16x32_bf16(
              aR[ks][i], bC[ch][ks][j], acc[rh * 4 + i][ch * 2 + j], 0, 0, 0);
  };

#define LGKM0 asm volatile("s_waitcnt lgkmcnt(0)" ::: "memory"); \
              __builtin_amdgcn_sched_barrier(0)
#define PRIO1 __builtin_amdgcn_s_setprio(1)
#define PRIO0 __builtin_amdgcn_s_setprio(0)
#define BAR   __builtin_amdgcn_s_barrier()

  // prologue: tile0 (A0 A1 B0 B1) + tile1 (B0 B1)  = 12 loads/thread
  stage(Ag, by, 0, 0, 0, As); stage(Ag, by, 0, 1, 0, As);
  stage(Bt, bx, 0, 0, 0, Bs); stage(Bt, bx, 0, 1, 0, Bs);
  stage(Bt, bx, 1, 0, 1, Bs); stage(Bt, bx, 1, 1, 1, Bs);

  for (int it = 0; it < NT / 2; ++it) {
    const int t0 = 2 * it;
    const bool more = (t0 + 2 < NT);
    const bool more3 = (t0 + 3 < NT);
    // ---- p0: (r0,c0) of tile t0 (buf0) ----
    stage(Ag, by, 1, 0, t0 + 1, As);
    asm volatile("s_waitcnt vmcnt(6)" ::: "memory");
    BAR;
    dsA(0, 0); dsB(0, 0);
    LGKM0; PRIO1; mfma16(0, 0); PRIO0; BAR;
    // ---- p1: (r0,c1) ----
    dsB(0, 1);
    stage(Ag, by, 1, 1, t0 + 1, As);
    LGKM0; PRIO1; mfma16(0, 1); PRIO0; BAR;
    // ---- p2: (r1,c0) ----
    dsA(0, 1);
    if (more) stage(Bt, bx, 0, 0, t0 + 2, Bs);
    LGKM0; PRIO1; mfma16(1, 0); PRIO0; BAR;
    // ---- p3: (r1,c1) ----
    if (more) stage(Bt, bx, 0, 1, t0 + 2, Bs);
    PRIO1; mfma16(1, 1); PRIO0; BAR;
    // ---- p4: (r0,c0) of tile t0+1 (buf1) ----
    if (more) stage(Ag, by, 0, 0, t0 + 2, As);
    if (more) { asm volatile("s_waitcnt vmcnt(6)" ::: "memory"); }
    else      { asm volatile("s_waitcnt vmcnt(0)" ::: "memory"); }
    BAR;
    dsA(1, 0); dsB(1, 0);
    LGKM0; PRIO1; mfma16(0, 0); PRIO0; BAR;
    // ---- p5: (r0,c1) ----
    dsB(1, 1);
    if (more) stage(Ag, by, 0, 1, t0 + 2, As);
    LGKM0; PRIO1; mfma16(0, 1); PRIO0; BAR;
    // ---- p6: (r1,c0) ----
    dsA(1, 1);
    if (more3) stage(Bt, bx, 1, 0, t0 + 3, Bs);
    LGKM0; PRIO1; mfma16(1, 0); PRIO0; BAR;
    // ---- p7: (r1,c1) ----
    if (more3) stage(Bt, bx, 1, 1, t0 + 3, Bs);
    PRIO1; mfma16(1, 1); PRIO0; BAR;
  }
#undef LGKM0
#undef PRIO1
#undef PRIO0
#undef BAR

  // epilogue: C/D frag layout col = lane&15, row = kq*4 + r
  const int rg = kq * 4;
#pragma unroll
  for (int n = 0; n < 4; ++n) {
    const int gn = bx * 256 + wc * 64 + (n >> 1) * 32 + (n & 1) * 16 + fr;
    const float bvl = bias[gn];
#pragma unroll
    for (int m = 0; m < 8; ++m) {
#pragma unroll
      for (int r = 0; r < 4; ++r) {
        const int lrow = wr * 128 + (m >> 2) * 64 + (m & 3) * 16 + rg + r;
        const int gm = by * 256 + lrow;
        float v = acc[m][n][r] + bvl;
        if constexpr (RELU_OUT_BF16) {
          v = fmaxf(v, 0.f);
          size_t a = (((size_t)(gm >> 7) * (N >> 3) + (gn >> 3)) << 10) +
                     ((gm & 127) << 3) + (gn & 7);
          ((unsigned short*)Cptr)[a] = f2bf(v);
        } else {
          if (gm < M_valid) ((float*)Cptr)[(size_t)gm * N + gn] = v;
        }
      }
    }
  }
}

extern "C" void kernel_launch(void* const* d_in, const int* in_sizes, int n_in,
                              void* d_out, int out_size, void* d_ws, size_t ws_size,
                              hipStream_t stream) {
  const float* x    = (const float*)d_in[0];
  const int*   ei   = (const int*)d_in[1];
  const float* cond = (const float*)d_in[2];
  const float* Wk   = (const float*)d_in[3];
  const float* W1   = (const float*)d_in[4];
  const float* b1   = (const float*)d_in[5];
  const float* W2   = (const float*)d_in[6];
  const float* b2   = (const float*)d_in[7];
  float* out = (float*)d_out;

  char* ws = (char*)d_ws;
  size_t off = 0;
  auto alloc = [&](size_t b) { size_t p = off; off += (b + 255) & ~(size_t)255; return p; };
  float* key = (float*)(ws + alloc(2 * D * sizeof(float)));
  float* nki = (float*)(ws + alloc(NNODES * sizeof(float)));
  float* nkj = (float*)(ws + alloc(NNODES * sizeof(float)));
  int* deg    = (int*)(ws + alloc(NNODES * sizeof(int)));
  int* rowptr = (int*)(ws + alloc((NNODES + 1) * sizeof(int)));
  int* cursor = (int*)(ws + alloc(NNODES * sizeof(int)));
  int* blktot = (int*)(ws + alloc(SCAN_BLOCKS * sizeof(int)));
  int* blkoff = (int*)(ws + alloc(SCAN_BLOCKS * sizeof(int)));
  int* scol      = (int*)(ws + alloc(NEDGES * sizeof(int)));
  float* salpha  = (float*)(ws + alloc(NEDGES * sizeof(float)));
  unsigned short* xb  = (unsigned short*)(ws + alloc((size_t)NNODES * D * 2));  // bf16 x, row-major
  unsigned short* W1t = (unsigned short*)(ws + alloc((size_t)H1 * D * 2));      // packed (R=H1,K=D)
  unsigned short* W2t = (unsigned short*)(ws + alloc((size_t)D * H1 * 2));      // packed (R=D,K=H1)
  unsigned short* Pb  = (unsigned short*)(ws + alloc((size_t)MPAD * D * 2));    // packed (R=MPAD,K=D)
  unsigned short* Hb  = (unsigned short*)(ws + alloc((size_t)MPAD * H1 * 2));   // packed (R=MPAD,K=H1)

  const int* row = ei;
  const int* col = ei + NEDGES;

  key_kernel<<<dim3((2 * D + 255) / 256), dim3(256), 0, stream>>>(cond, Wk, key);
  nodedot_kernel<<<dim3(NNODES * 64 / 256), dim3(256), 0, stream>>>(x, key, nki, nkj, xb);
  convw_kernel<<<dim3(D * H1 / 256), dim3(256), 0, stream>>>(W1, W2, W1t, W2t);

  // CSR build
  zero_deg_kernel<<<dim3(SCAN_BLOCKS), dim3(256), 0, stream>>>(deg);
  hist_kernel<<<dim3((NEDGES + 255) / 256), dim3(256), 0, stream>>>(row, deg);
  scan1_kernel<<<dim3(SCAN_BLOCKS), dim3(256), 0, stream>>>(deg, rowptr, blktot);
  scan2_kernel<<<dim3(1), dim3(256), 0, stream>>>(blktot, blkoff);
  scan3_kernel<<<dim3(SCAN_BLOCKS), dim3(256), 0, stream>>>(rowptr, blkoff, cursor);
  fill_kernel<<<dim3((NEDGES + 255) / 256), dim3(256), 0, stream>>>(row, col, nki, nkj,
                                                                    cursor, scol, salpha);
  // aggregate: Pb = bf16(xb + segment_sum(alpha * xb[col])), packed
  agg_kernel<<<dim3(NNODES * 64 / 256 + 1), dim3(256), 0, stream>>>(xb, rowptr, scol, salpha, Pb);

  // GEMM1: Hb = relu(Pb @ W1 + b1)  [M=50176, K=512, N=1024]  grid 4x196 = 784
  gemm8p<512, true><<<dim3(H1 / 256, MPAD / 256), dim3(512), 0, stream>>>(
      Pb, W1t, b1, Hb, NNODES, H1);
  // GEMM2: out = Hb @ W2 + b2       [M=50176, K=1024, N=512]  grid 2x196 = 392
  gemm8p<1024, false><<<dim3(D / 256, MPAD / 256), dim3(512), 0, stream>>>(
      Hb, W2t, b2, out, NNODES, D);
}

// Round 11
// 364.207 us; speedup vs baseline: 1.7460x; 1.0915x over previous
//
#include <hip/hip_runtime.h>

#define D 512
#define H1 1024
#define NNODES 50000
#define NEDGES 400000
#define MPAD 50176   // 392 * 128
#define NEG_SLOPE 0.2f
#define SCAN_BLOCKS 196   // 196*256 = 50176 >= 50000

// prep kernel block partition
#define NB_ND 12500   // nodedot: 50000 waves
#define NB_CW 2048    // convw: 524288 elems
#define NB_HI 1563    // hist: 400128 threads

typedef __attribute__((ext_vector_type(8))) short bf16x8;
typedef __attribute__((ext_vector_type(8))) unsigned short u16x8;
typedef __attribute__((ext_vector_type(4))) float f32x4;
typedef __attribute__((ext_vector_type(4))) unsigned int u32x4;

// packed operand layout for GEMM staging:
// addr(r, k) = ((r>>7)*(K>>3) + (k>>3))*1024 + (r&127)*8 + (k&7)
// -> a 64-lane global_load_lds segment (64 rows x one 8-k chunk) is one
//    contiguous 1KB burst; LDS image is linear and conflict-free (2-way).

__device__ __forceinline__ unsigned short f2bf(float f) {
  unsigned int u = __float_as_uint(f);
  unsigned int r = u + 0x7FFFu + ((u >> 16) & 1u);
  return (unsigned short)(r >> 16);
}
__device__ __forceinline__ float bf2f(unsigned short h) {
  return __uint_as_float((unsigned int)h << 16);
}

__device__ __forceinline__ void gl_lds16(const void* g, void* l) {
  __builtin_amdgcn_global_load_lds(
      (const __attribute__((address_space(1))) void*)g,
      (__attribute__((address_space(3))) void*)l, 16, 0, 0);
}

// key[j] = sum_i cond[i] * Wk[i][j],  Wk is (256, 2D) row-major
__global__ void key_kernel(const float* __restrict__ cond, const float* __restrict__ Wk,
                           float* __restrict__ key) {
  int j = blockIdx.x * blockDim.x + threadIdx.x;
  if (j >= 2 * D) return;
  float s = 0.f;
#pragma unroll 8
  for (int i = 0; i < 256; ++i) s += cond[i] * Wk[i * (2 * D) + j];
  key[j] = s;
}

// fused independent pre-work: nodedot | convw | hist  (key must be done; deg zeroed)
__global__ __launch_bounds__(256) void prep_kernel(
    const float* __restrict__ x, const float* __restrict__ key,
    const float* __restrict__ W1, const float* __restrict__ W2,
    const int* __restrict__ row,
    float* __restrict__ nki, float* __restrict__ nkj, unsigned short* __restrict__ xb,
    unsigned short* __restrict__ W1t, unsigned short* __restrict__ W2t,
    int* __restrict__ deg) {
  const int b = blockIdx.x;
  const int tid = threadIdx.x;
  if (b < NB_ND) {
    // ---- nodedot: one wave per node; also emit xb = bf16(x) row-major ----
    int wid = (b * 256 + tid) >> 6;
    int lane = tid & 63;
    const float4* xr = (const float4*)(x + (size_t)wid * D);
    float4 p0 = xr[2 * lane], p1 = xr[2 * lane + 1];
    const float4* kia = (const float4*)key;
    const float4* kja = (const float4*)(key + D);
    float4 q0 = kia[2 * lane], q1 = kia[2 * lane + 1];
    float4 r0 = kja[2 * lane], r1 = kja[2 * lane + 1];
    float a = p0.x * q0.x + p0.y * q0.y + p0.z * q0.z + p0.w * q0.w +
              p1.x * q1.x + p1.y * q1.y + p1.z * q1.z + p1.w * q1.w;
    float bb = p0.x * r0.x + p0.y * r0.y + p0.z * r0.z + p0.w * r0.w +
               p1.x * r1.x + p1.y * r1.y + p1.z * r1.z + p1.w * r1.w;
    u16x8 h;
    h[0] = f2bf(p0.x); h[1] = f2bf(p0.y); h[2] = f2bf(p0.z); h[3] = f2bf(p0.w);
    h[4] = f2bf(p1.x); h[5] = f2bf(p1.y); h[6] = f2bf(p1.z); h[7] = f2bf(p1.w);
    *(u16x8*)(xb + (size_t)wid * D + 8 * lane) = h;
#pragma unroll
    for (int off = 32; off > 0; off >>= 1) {
      a += __shfl_xor(a, off);
      bb += __shfl_xor(bb, off);
    }
    if (lane == 0) { nki[wid] = a; nkj[wid] = bb; }
  } else if (b < NB_ND + NB_CW) {
    // ---- convw: W1 -> W1t packed (R=H1,K=D); W2 -> W2t packed (R=D,K=H1) ----
    int idx = (b - NB_ND) * 256 + tid;
    {
      int k = idx / H1, n = idx % H1;
      size_t a = (((size_t)(n >> 7) * (D >> 3) + (k >> 3)) << 10) + ((n & 127) << 3) + (k & 7);
      W1t[a] = f2bf(W1[idx]);
    }
    {
      int k = idx / D, n = idx % D;
      size_t a = (((size_t)(n >> 7) * (H1 >> 3) + (k >> 3)) << 10) + ((n & 127) << 3) + (k & 7);
      W2t[a] = f2bf(W2[idx]);
    }
  } else {
    // ---- hist ----
    int e = (b - NB_ND - NB_CW) * 256 + tid;
    if (e < NEDGES) atomicAdd(&deg[row[e]], 1);
  }
}

// ---- CSR scans ----
__global__ void scan1_kernel(const int* __restrict__ deg, int* __restrict__ rowptr,
                             int* __restrict__ blktot) {
  __shared__ int s[256];
  int tid = threadIdx.x;
  int i = blockIdx.x * 256 + tid;
  int v = (i < NNODES) ? deg[i] : 0;
  s[tid] = v;
  __syncthreads();
#pragma unroll
  for (int off = 1; off < 256; off <<= 1) {
    int t = (tid >= off) ? s[tid - off] : 0;
    __syncthreads();
    s[tid] += t;
    __syncthreads();
  }
  if (i < NNODES) rowptr[i] = s[tid] - v;
  if (tid == 255) blktot[blockIdx.x] = s[255];
}

__global__ void scan2_kernel(int* __restrict__ blktot, int* __restrict__ blkoff) {
  __shared__ int s[256];
  int tid = threadIdx.x;
  int v = (tid < SCAN_BLOCKS) ? blktot[tid] : 0;
  s[tid] = v;
  __syncthreads();
#pragma unroll
  for (int off = 1; off < 256; off <<= 1) {
    int t = (tid >= off) ? s[tid - off] : 0;
    __syncthreads();
    s[tid] += t;
    __syncthreads();
  }
  if (tid < SCAN_BLOCKS) blkoff[tid] = s[tid] - v;
}

__global__ void scan3_kernel(int* __restrict__ rowptr, const int* __restrict__ blkoff,
                             int* __restrict__ cursor) {
  int i = blockIdx.x * blockDim.x + threadIdx.x;
  if (i < NNODES) {
    int v = rowptr[i] + blkoff[blockIdx.x];
    rowptr[i] = v;
    cursor[i] = v;
  }
  if (i == 0) rowptr[NNODES] = NEDGES;
}

// fill: pure permutation now — place col into CSR slot of its row
__global__ void fill_kernel(const int* __restrict__ row, const int* __restrict__ col,
                            int* __restrict__ cursor, int* __restrict__ scol) {
  int e = blockIdx.x * blockDim.x + threadIdx.x;
  if (e >= NEDGES) return;
  int pos = atomicAdd(&cursor[row[e]], 1);
  scol[pos] = col[e];
}

// one wave per node: Pb[n] = bf16(xb[n] + sum_e sigmoid(leaky(nki[c]+nkj[n])) * xb[c]),
// alpha computed inline (wave-uniform scalar path); packed output.
__global__ __launch_bounds__(256) void agg_kernel(
    const unsigned short* __restrict__ xb, const int* __restrict__ rowptr,
    const int* __restrict__ scol, const float* __restrict__ nki,
    const float* __restrict__ nkj, unsigned short* __restrict__ Pb) {
  int n = (blockIdx.x * blockDim.x + threadIdx.x) >> 6;
  int lane = threadIdx.x & 63;
  if (n >= NNODES) return;
  int beg = rowptr[n], end = rowptr[n + 1];
  const float nkjn = nkj[n];
  u16x8 self = *(const u16x8*)(xb + (size_t)n * D + 8 * lane);
  float sa[8], sb[8];
#pragma unroll
  for (int q = 0; q < 8; ++q) { sa[q] = bf2f(self[q]); sb[q] = 0.f; }
  auto alpha = [&](int c) {
    float a = nki[c] + nkjn;
    a = (a >= 0.f) ? a : NEG_SLOPE * a;
    return 1.f / (1.f + expf(-a));
  };
  int e = beg;
  for (; e + 1 < end; e += 2) {
    int c0 = scol[e], c1 = scol[e + 1];
    u16x8 w0 = *(const u16x8*)(xb + (size_t)c0 * D + 8 * lane);
    u16x8 w1 = *(const u16x8*)(xb + (size_t)c1 * D + 8 * lane);
    float al0 = alpha(c0), al1 = alpha(c1);
#pragma unroll
    for (int q = 0; q < 8; ++q) {
      sa[q] += al0 * bf2f(w0[q]);
      sb[q] += al1 * bf2f(w1[q]);
    }
  }
  if (e < end) {
    int c0 = scol[e];
    u16x8 w0 = *(const u16x8*)(xb + (size_t)c0 * D + 8 * lane);
    float al0 = alpha(c0);
#pragma unroll
    for (int q = 0; q < 8; ++q) sa[q] += al0 * bf2f(w0[q]);
  }
  u16x8 h;
#pragma unroll
  for (int q = 0; q < 8; ++q) h[q] = f2bf(sa[q] + sb[q]);
  *(u16x8*)(Pb + (((size_t)(n >> 7) * (D >> 3) + lane) << 10) + ((n & 127) << 3)) = h;
}

// ---- R5-proven GEMM: C = act(A @ Bt^T + bias). A, Bt PACKED. M padded to 128.
// m97 structure: tile 128x128, BK=64, coalesced global_load_lds x16 into linear
// chunked LDS [kc][row][8], 4 waves 2x2, 16x16x32 MFMA, XCD-chunked swizzle.
template <bool RELU_OUT_BF16>
__global__ __launch_bounds__(256) void gemm_kernel(
    const unsigned short* __restrict__ Ag, const unsigned short* __restrict__ Bt,
    const float* __restrict__ bias, void* __restrict__ Cptr, int M_valid, int K, int N) {
  __shared__ unsigned short As[8 * 128 * 8];  // [kc][row][8], 16 KB
  __shared__ unsigned short Bs[8 * 128 * 8];

  // bijective XCD-chunked swizzle
  const int G = gridDim.x * gridDim.y;
  const int orig = blockIdx.y * gridDim.x + blockIdx.x;
  const int qq = G >> 3, rr = G & 7;
  const int xcd = orig & 7, loc = orig >> 3;
  const int wg = (xcd < rr ? xcd * (qq + 1) : rr * (qq + 1) + (xcd - rr) * qq) + loc;
  const int bx = wg % gridDim.x;
  const int by = wg / gridDim.x;

  const int tid = threadIdx.x;
  const int lane = tid & 63;
  const int wave = tid >> 6;
  const int wm = (wave >> 1) * 64;
  const int wn = (wave & 1) * 64;
  const int n0 = bx * 128;
  const int fr = lane & 15;
  const int kq = lane >> 4;  // 0..3

  const unsigned short* Apan = Ag + ((size_t)by * (K >> 3) << 10);
  const unsigned short* Bpan = Bt + ((size_t)bx * (K >> 3) << 10);

  f32x4 acc[4][4];
#pragma unroll
  for (int i = 0; i < 4; ++i)
#pragma unroll
    for (int j = 0; j < 4; ++j)
#pragma unroll
      for (int r = 0; r < 4; ++r) acc[i][j][r] = 0.f;

  for (int k0 = 0; k0 < K; k0 += 64) {
#pragma unroll
    for (int ss = 0; ss < 4; ++ss) {
      int s = wave * 4 + ss;
      int rbase = (s & 1) * 64;
      int kca = (k0 >> 3) + (s >> 1);
      gl_lds16(Apan + ((size_t)kca << 10) + (rbase + lane) * 8, &As[s * 512]);
      gl_lds16(Bpan + ((size_t)kca << 10) + (rbase + lane) * 8, &Bs[s * 512]);
    }
    __syncthreads();

#pragma unroll
    for (int h = 0; h < 2; ++h) {
      const int kc = h * 4 + kq;
      bf16x8 af[4], bfr[4];
#pragma unroll
      for (int i = 0; i < 4; ++i)
        af[i] = *(const bf16x8*)&As[(kc * 128 + wm + i * 16 + fr) * 8];
#pragma unroll
      for (int j = 0; j < 4; ++j)
        bfr[j] = *(const bf16x8*)&Bs[(kc * 128 + wn + j * 16 + fr) * 8];
#pragma unroll
      for (int i = 0; i < 4; ++i)
#pragma unroll
        for (int j = 0; j < 4; ++j)
          acc[i][j] = __builtin_amdgcn_mfma_f32_16x16x32_bf16(af[i], bfr[j], acc[i][j], 0, 0, 0);
    }
    __syncthreads();
  }

  // epilogue: C/D layout col = lane&15, row = (lane>>4)*4 + reg
  const int rg = kq * 4;
#pragma unroll
  for (int i = 0; i < 4; ++i) {
#pragma unroll
    for (int j = 0; j < 4; ++j) {
      int gn = n0 + wn + j * 16 + fr;
      float bv = bias[gn];
#pragma unroll
      for (int r = 0; r < 4; ++r) {
        int lr = wm + i * 16 + rg + r;
        float v = acc[i][j][r] + bv;
        if constexpr (RELU_OUT_BF16) {
          v = fmaxf(v, 0.f);
          size_t a = (((size_t)by * (N >> 3) + (gn >> 3)) << 10) + (lr << 3) + (gn & 7);
          ((unsigned short*)Cptr)[a] = f2bf(v);
        } else {
          int gm = by * 128 + lr;
          if (gm < M_valid) ((float*)Cptr)[(size_t)gm * N + gn] = v;
        }
      }
    }
  }
}

extern "C" void kernel_launch(void* const* d_in, const int* in_sizes, int n_in,
                              void* d_out, int out_size, void* d_ws, size_t ws_size,
                              hipStream_t stream) {
  const float* x    = (const float*)d_in[0];
  const int*   ei   = (const int*)d_in[1];
  const float* cond = (const float*)d_in[2];
  const float* Wk   = (const float*)d_in[3];
  const float* W1   = (const float*)d_in[4];
  const float* b1   = (const float*)d_in[5];
  const float* W2   = (const float*)d_in[6];
  const float* b2   = (const float*)d_in[7];
  float* out = (float*)d_out;

  char* ws = (char*)d_ws;
  size_t off = 0;
  auto alloc = [&](size_t b) { size_t p = off; off += (b + 255) & ~(size_t)255; return p; };
  float* key = (float*)(ws + alloc(2 * D * sizeof(float)));
  float* nki = (float*)(ws + alloc(NNODES * sizeof(float)));
  float* nkj = (float*)(ws + alloc(NNODES * sizeof(float)));
  int* deg    = (int*)(ws + alloc(NNODES * sizeof(int)));
  int* rowptr = (int*)(ws + alloc((NNODES + 1) * sizeof(int)));
  int* cursor = (int*)(ws + alloc(NNODES * sizeof(int)));
  int* blktot = (int*)(ws + alloc(SCAN_BLOCKS * sizeof(int)));
  int* blkoff = (int*)(ws + alloc(SCAN_BLOCKS * sizeof(int)));
  int* scol      = (int*)(ws + alloc(NEDGES * sizeof(int)));
  unsigned short* xb  = (unsigned short*)(ws + alloc((size_t)NNODES * D * 2));  // bf16 x, row-major
  unsigned short* W1t = (unsigned short*)(ws + alloc((size_t)H1 * D * 2));      // packed (R=H1,K=D)
  unsigned short* W2t = (unsigned short*)(ws + alloc((size_t)D * H1 * 2));      // packed (R=D,K=H1)
  unsigned short* Pb  = (unsigned short*)(ws + alloc((size_t)MPAD * D * 2));    // packed (R=MPAD,K=D)
  unsigned short* Hb  = (unsigned short*)(ws + alloc((size_t)MPAD * H1 * 2));   // packed (R=MPAD,K=H1)

  const int* row = ei;
  const int* col = ei + NEDGES;

  hipMemsetAsync(deg, 0, NNODES * sizeof(int), stream);
  key_kernel<<<dim3(4), dim3(256), 0, stream>>>(cond, Wk, key);
  // fused: nodedot | convw | hist
  prep_kernel<<<dim3(NB_ND + NB_CW + NB_HI), dim3(256), 0, stream>>>(
      x, key, W1, W2, row, nki, nkj, xb, W1t, W2t, deg);

  scan1_kernel<<<dim3(SCAN_BLOCKS), dim3(256), 0, stream>>>(deg, rowptr, blktot);
  scan2_kernel<<<dim3(1), dim3(256), 0, stream>>>(blktot, blkoff);
  scan3_kernel<<<dim3(SCAN_BLOCKS), dim3(256), 0, stream>>>(rowptr, blkoff, cursor);
  fill_kernel<<<dim3((NEDGES + 255) / 256), dim3(256), 0, stream>>>(row, col, cursor, scol);
  // aggregate: Pb = bf16(xb + segment_sum(alpha * xb[col])), alpha inline, packed
  agg_kernel<<<dim3(NB_ND), dim3(256), 0, stream>>>(xb, rowptr, scol, nki, nkj, Pb);

  // GEMM1: Hb = relu(Pb @ W1 + b1)  [M=50176, K=512, N=1024]  grid 8 x 392
  gemm_kernel<true><<<dim3(H1 / 128, MPAD / 128), dim3(256), 0, stream>>>(
      Pb, W1t, b1, Hb, NNODES, D, H1);
  // GEMM2: out = Hb @ W2 + b2       [M=50176, K=1024, N=512]  grid 4 x 392
  gemm_kernel<false><<<dim3(D / 128, MPAD / 128), dim3(256), 0, stream>>>(
      Hb, W2t, b2, out, NNODES, H1, D);
}

// Round 12
// 352.925 us; speedup vs baseline: 1.8018x; 1.0320x over previous
//
#include <hip/hip_runtime.h>

#define D 512
#define H1 1024
#define NNODES 50000
#define NEDGES 400000
#define MPAD 50176   // 392 * 128
#define NEG_SLOPE 0.2f
#define SCAN_BLOCKS 196   // 196*256 = 50176 >= 50000

// prep kernel block partition
#define NB_ND 12500   // nodedot: 50000 waves
#define NB_CW 2048    // convw: 524288 elems
#define NB_HI 1563    // hist: 400128 threads

typedef __attribute__((ext_vector_type(8))) short bf16x8;
typedef __attribute__((ext_vector_type(8))) unsigned short u16x8;
typedef __attribute__((ext_vector_type(16))) float f32x16;

// packed operand layout for GEMM staging:
// addr(r, k) = ((r>>7)*(K>>3) + (k>>3))*1024 + (r&127)*8 + (k&7)
// -> a 64-lane global_load_lds segment (64 rows x one 8-k chunk) is one
//    contiguous 1KB burst; LDS image is linear and conflict-free.

__device__ __forceinline__ unsigned short f2bf(float f) {
  unsigned int u = __float_as_uint(f);
  unsigned int r = u + 0x7FFFu + ((u >> 16) & 1u);
  return (unsigned short)(r >> 16);
}
__device__ __forceinline__ float bf2f(unsigned short h) {
  return __uint_as_float((unsigned int)h << 16);
}

__device__ __forceinline__ void gl_lds16(const void* g, void* l) {
  __builtin_amdgcn_global_load_lds(
      (const __attribute__((address_space(1))) void*)g,
      (__attribute__((address_space(3))) void*)l, 16, 0, 0);
}

// key[j] = sum_i cond[i] * Wk[i][j],  Wk is (256, 2D) row-major
__global__ void key_kernel(const float* __restrict__ cond, const float* __restrict__ Wk,
                           float* __restrict__ key) {
  int j = blockIdx.x * blockDim.x + threadIdx.x;
  if (j >= 2 * D) return;
  float s = 0.f;
#pragma unroll 8
  for (int i = 0; i < 256; ++i) s += cond[i] * Wk[i * (2 * D) + j];
  key[j] = s;
}

// fused independent pre-work: nodedot | convw | hist  (key must be done; deg zeroed)
__global__ __launch_bounds__(256) void prep_kernel(
    const float* __restrict__ x, const float* __restrict__ key,
    const float* __restrict__ W1, const float* __restrict__ W2,
    const int* __restrict__ row,
    float* __restrict__ nki, float* __restrict__ nkj, unsigned short* __restrict__ xb,
    unsigned short* __restrict__ W1t, unsigned short* __restrict__ W2t,
    int* __restrict__ deg) {
  const int b = blockIdx.x;
  const int tid = threadIdx.x;
  if (b < NB_ND) {
    // ---- nodedot: one wave per node; also emit xb = bf16(x) row-major ----
    int wid = (b * 256 + tid) >> 6;
    int lane = tid & 63;
    const float4* xr = (const float4*)(x + (size_t)wid * D);
    float4 p0 = xr[2 * lane], p1 = xr[2 * lane + 1];
    const float4* kia = (const float4*)key;
    const float4* kja = (const float4*)(key + D);
    float4 q0 = kia[2 * lane], q1 = kia[2 * lane + 1];
    float4 r0 = kja[2 * lane], r1 = kja[2 * lane + 1];
    float a = p0.x * q0.x + p0.y * q0.y + p0.z * q0.z + p0.w * q0.w +
              p1.x * q1.x + p1.y * q1.y + p1.z * q1.z + p1.w * q1.w;
    float bb = p0.x * r0.x + p0.y * r0.y + p0.z * r0.z + p0.w * r0.w +
               p1.x * r1.x + p1.y * r1.y + p1.z * r1.z + p1.w * r1.w;
    u16x8 h;
    h[0] = f2bf(p0.x); h[1] = f2bf(p0.y); h[2] = f2bf(p0.z); h[3] = f2bf(p0.w);
    h[4] = f2bf(p1.x); h[5] = f2bf(p1.y); h[6] = f2bf(p1.z); h[7] = f2bf(p1.w);
    *(u16x8*)(xb + (size_t)wid * D + 8 * lane) = h;
#pragma unroll
    for (int off = 32; off > 0; off >>= 1) {
      a += __shfl_xor(a, off);
      bb += __shfl_xor(bb, off);
    }
    if (lane == 0) { nki[wid] = a; nkj[wid] = bb; }
  } else if (b < NB_ND + NB_CW) {
    // ---- convw: W1 -> W1t packed (R=H1,K=D); W2 -> W2t packed (R=D,K=H1) ----
    int idx = (b - NB_ND) * 256 + tid;
    {
      int k = idx / H1, n = idx % H1;
      size_t a = (((size_t)(n >> 7) * (D >> 3) + (k >> 3)) << 10) + ((n & 127) << 3) + (k & 7);
      W1t[a] = f2bf(W1[idx]);
    }
    {
      int k = idx / D, n = idx % D;
      size_t a = (((size_t)(n >> 7) * (H1 >> 3) + (k >> 3)) << 10) + ((n & 127) << 3) + (k & 7);
      W2t[a] = f2bf(W2[idx]);
    }
  } else {
    // ---- hist ----
    int e = (b - NB_ND - NB_CW) * 256 + tid;
    if (e < NEDGES) atomicAdd(&deg[row[e]], 1);
  }
}

// ---- CSR scans ----
__global__ void scan1_kernel(const int* __restrict__ deg, int* __restrict__ rowptr,
                             int* __restrict__ blktot) {
  __shared__ int s[256];
  int tid = threadIdx.x;
  int i = blockIdx.x * 256 + tid;
  int v = (i < NNODES) ? deg[i] : 0;
  s[tid] = v;
  __syncthreads();
#pragma unroll
  for (int off = 1; off < 256; off <<= 1) {
    int t = (tid >= off) ? s[tid - off] : 0;
    __syncthreads();
    s[tid] += t;
    __syncthreads();
  }
  if (i < NNODES) rowptr[i] = s[tid] - v;
  if (tid == 255) blktot[blockIdx.x] = s[255];
}

// fused scan2+scan3: every block redundantly scans the 196 block totals,
// takes its own exclusive offset, applies to rowptr and inits cursor.
__global__ void scan23_kernel(int* __restrict__ rowptr, const int* __restrict__ blktot,
                              int* __restrict__ cursor) {
  __shared__ int s[256];
  int tid = threadIdx.x;
  int v = (tid < SCAN_BLOCKS) ? blktot[tid] : 0;
  s[tid] = v;
  __syncthreads();
#pragma unroll
  for (int off = 1; off < 256; off <<= 1) {
    int t = (tid >= off) ? s[tid - off] : 0;
    __syncthreads();
    s[tid] += t;
    __syncthreads();
  }
  const int blkoff = s[blockIdx.x] - blktot[blockIdx.x];  // exclusive
  int i = blockIdx.x * 256 + tid;
  if (i < NNODES) {
    int val = rowptr[i] + blkoff;
    rowptr[i] = val;
    cursor[i] = val;
  }
  if (i == 0) rowptr[NNODES] = NEDGES;
}

// fill: pure permutation — place col into CSR slot of its row
__global__ void fill_kernel(const int* __restrict__ row, const int* __restrict__ col,
                            int* __restrict__ cursor, int* __restrict__ scol) {
  int e = blockIdx.x * blockDim.x + threadIdx.x;
  if (e >= NEDGES) return;
  int pos = atomicAdd(&cursor[row[e]], 1);
  scol[pos] = col[e];
}

// one wave per node: Pb[n] = bf16(xb[n] + sum_e sigmoid(leaky(nki[c]+nkj[n])) * xb[c])
__global__ __launch_bounds__(256) void agg_kernel(
    const unsigned short* __restrict__ xb, const int* __restrict__ rowptr,
    const int* __restrict__ scol, const float* __restrict__ nki,
    const float* __restrict__ nkj, unsigned short* __restrict__ Pb) {
  int n = (blockIdx.x * blockDim.x + threadIdx.x) >> 6;
  int lane = threadIdx.x & 63;
  if (n >= NNODES) return;
  int beg = rowptr[n], end = rowptr[n + 1];
  const float nkjn = nkj[n];
  u16x8 self = *(const u16x8*)(xb + (size_t)n * D + 8 * lane);
  float sa[8], sb[8];
#pragma unroll
  for (int q = 0; q < 8; ++q) { sa[q] = bf2f(self[q]); sb[q] = 0.f; }
  auto alpha = [&](int c) {
    float a = nki[c] + nkjn;
    a = (a >= 0.f) ? a : NEG_SLOPE * a;
    return 1.f / (1.f + expf(-a));
  };
  int e = beg;
  for (; e + 1 < end; e += 2) {
    int c0 = scol[e], c1 = scol[e + 1];
    u16x8 w0 = *(const u16x8*)(xb + (size_t)c0 * D + 8 * lane);
    u16x8 w1 = *(const u16x8*)(xb + (size_t)c1 * D + 8 * lane);
    float al0 = alpha(c0), al1 = alpha(c1);
#pragma unroll
    for (int q = 0; q < 8; ++q) {
      sa[q] += al0 * bf2f(w0[q]);
      sb[q] += al1 * bf2f(w1[q]);
    }
  }
  if (e < end) {
    int c0 = scol[e];
    u16x8 w0 = *(const u16x8*)(xb + (size_t)c0 * D + 8 * lane);
    float al0 = alpha(c0);
#pragma unroll
    for (int q = 0; q < 8; ++q) sa[q] += al0 * bf2f(w0[q]);
  }
  u16x8 h;
#pragma unroll
  for (int q = 0; q < 8; ++q) h[q] = f2bf(sa[q] + sb[q]);
  *(u16x8*)(Pb + (((size_t)(n >> 7) * (D >> 3) + lane) << 10) + ((n & 127) << 3)) = h;
}

// ---- GEMM (m97 structure, 32x32x16 MFMA): C = act(A @ Bt^T + bias) ----
// A, Bt PACKED. Tile 128x128, BK=64, global_load_lds x16 into linear chunked
// LDS [kc][row][8], 4 waves 2x2, wave tile 64x64 = 2x2 of 32x32x16 MFMA
// (half the MFMA instruction count of 16x16x32 at identical ds_read traffic).
// A/B frag: row(col)=lane&31, k=(lane>>5)*8+[0..7].
// C/D frag: col=lane&31, row=(reg&3)+8*(reg>>2)+4*(lane>>5)  [m74/m101].
template <bool RELU_OUT_BF16>
__global__ __launch_bounds__(256) void gemm_kernel(
    const unsigned short* __restrict__ Ag, const unsigned short* __restrict__ Bt,
    const float* __restrict__ bias, void* __restrict__ Cptr, int M_valid, int K, int N) {
  __shared__ unsigned short As[8 * 128 * 8];  // [kc][row][8], 16 KB
  __shared__ unsigned short Bs[8 * 128 * 8];

  // bijective XCD-chunked swizzle
  const int G = gridDim.x * gridDim.y;
  const int orig = blockIdx.y * gridDim.x + blockIdx.x;
  const int qq = G >> 3, rr = G & 7;
  const int xcd = orig & 7, loc = orig >> 3;
  const int wg = (xcd < rr ? xcd * (qq + 1) : rr * (qq + 1) + (xcd - rr) * qq) + loc;
  const int bx = wg % gridDim.x;
  const int by = wg / gridDim.x;

  const int tid = threadIdx.x;
  const int lane = tid & 63;
  const int wave = tid >> 6;
  const int wm = (wave >> 1) * 64;
  const int wn = (wave & 1) * 64;
  const int n0 = bx * 128;
  const int lane31 = lane & 31;
  const int kh = lane >> 5;  // 0..1

  const unsigned short* Apan = Ag + ((size_t)by * (K >> 3) << 10);
  const unsigned short* Bpan = Bt + ((size_t)bx * (K >> 3) << 10);

  f32x16 acc[2][2];
#pragma unroll
  for (int i = 0; i < 2; ++i)
#pragma unroll
    for (int j = 0; j < 2; ++j)
#pragma unroll
      for (int r = 0; r < 16; ++r) acc[i][j][r] = 0.f;

  for (int k0 = 0; k0 < K; k0 += 64) {
#pragma unroll
    for (int ss = 0; ss < 4; ++ss) {
      int s = wave * 4 + ss;
      int rbase = (s & 1) * 64;
      int kca = (k0 >> 3) + (s >> 1);
      gl_lds16(Apan + ((size_t)kca << 10) + (rbase + lane) * 8, &As[s * 512]);
      gl_lds16(Bpan + ((size_t)kca << 10) + (rbase + lane) * 8, &Bs[s * 512]);
    }
    __syncthreads();

#pragma unroll
    for (int ks = 0; ks < 4; ++ks) {  // 16-k steps
      const int kc = ks * 2 + kh;
      bf16x8 af[2], bfr[2];
#pragma unroll
      for (int i = 0; i < 2; ++i)
        af[i] = *(const bf16x8*)&As[(kc * 128 + wm + i * 32 + lane31) * 8];
#pragma unroll
      for (int j = 0; j < 2; ++j)
        bfr[j] = *(const bf16x8*)&Bs[(kc * 128 + wn + j * 32 + lane31) * 8];
#pragma unroll
      for (int i = 0; i < 2; ++i)
#pragma unroll
        for (int j = 0; j < 2; ++j)
          acc[i][j] = __builtin_amdgcn_mfma_f32_32x32x16_bf16(af[i], bfr[j], acc[i][j], 0, 0, 0);
    }
    __syncthreads();
  }

  // epilogue: C/D layout col=lane&31, row=(r&3)+8*(r>>2)+4*kh
#pragma unroll
  for (int i = 0; i < 2; ++i) {
#pragma unroll
    for (int j = 0; j < 2; ++j) {
      const int gn = n0 + wn + j * 32 + lane31;
      const float bv = bias[gn];
#pragma unroll
      for (int r = 0; r < 16; ++r) {
        const int lr = wm + i * 32 + 4 * kh + (r & 3) + 8 * (r >> 2);
        float v = acc[i][j][r] + bv;
        if constexpr (RELU_OUT_BF16) {
          v = fmaxf(v, 0.f);
          size_t a = (((size_t)by * (N >> 3) + (gn >> 3)) << 10) + (lr << 3) + (gn & 7);
          ((unsigned short*)Cptr)[a] = f2bf(v);
        } else {
          int gm = by * 128 + lr;
          if (gm < M_valid) ((float*)Cptr)[(size_t)gm * N + gn] = v;
        }
      }
    }
  }
}

extern "C" void kernel_launch(void* const* d_in, const int* in_sizes, int n_in,
                              void* d_out, int out_size, void* d_ws, size_t ws_size,
                              hipStream_t stream) {
  const float* x    = (const float*)d_in[0];
  const int*   ei   = (const int*)d_in[1];
  const float* cond = (const float*)d_in[2];
  const float* Wk   = (const float*)d_in[3];
  const float* W1   = (const float*)d_in[4];
  const float* b1   = (const float*)d_in[5];
  const float* W2   = (const float*)d_in[6];
  const float* b2   = (const float*)d_in[7];
  float* out = (float*)d_out;

  char* ws = (char*)d_ws;
  size_t off = 0;
  auto alloc = [&](size_t b) { size_t p = off; off += (b + 255) & ~(size_t)255; return p; };
  float* key = (float*)(ws + alloc(2 * D * sizeof(float)));
  float* nki = (float*)(ws + alloc(NNODES * sizeof(float)));
  float* nkj = (float*)(ws + alloc(NNODES * sizeof(float)));
  int* deg    = (int*)(ws + alloc(NNODES * sizeof(int)));
  int* rowptr = (int*)(ws + alloc((NNODES + 1) * sizeof(int)));
  int* cursor = (int*)(ws + alloc(NNODES * sizeof(int)));
  int* blktot = (int*)(ws + alloc(SCAN_BLOCKS * sizeof(int)));
  int* scol      = (int*)(ws + alloc(NEDGES * sizeof(int)));
  unsigned short* xb  = (unsigned short*)(ws + alloc((size_t)NNODES * D * 2));  // bf16 x, row-major
  unsigned short* W1t = (unsigned short*)(ws + alloc((size_t)H1 * D * 2));      // packed (R=H1,K=D)
  unsigned short* W2t = (unsigned short*)(ws + alloc((size_t)D * H1 * 2));      // packed (R=D,K=H1)
  unsigned short* Pb  = (unsigned short*)(ws + alloc((size_t)MPAD * D * 2));    // packed (R=MPAD,K=D)
  unsigned short* Hb  = (unsigned short*)(ws + alloc((size_t)MPAD * H1 * 2));   // packed (R=MPAD,K=H1)

  const int* row = ei;
  const int* col = ei + NEDGES;

  hipMemsetAsync(deg, 0, NNODES * sizeof(int), stream);
  key_kernel<<<dim3(4), dim3(256), 0, stream>>>(cond, Wk, key);
  // fused: nodedot | convw | hist
  prep_kernel<<<dim3(NB_ND + NB_CW + NB_HI), dim3(256), 0, stream>>>(
      x, key, W1, W2, row, nki, nkj, xb, W1t, W2t, deg);

  scan1_kernel<<<dim3(SCAN_BLOCKS), dim3(256), 0, stream>>>(deg, rowptr, blktot);
  scan23_kernel<<<dim3(SCAN_BLOCKS), dim3(256), 0, stream>>>(rowptr, blktot, cursor);
  fill_kernel<<<dim3((NEDGES + 255) / 256), dim3(256), 0, stream>>>(row, col, cursor, scol);
  // aggregate: Pb = bf16(xb + segment_sum(alpha * xb[col])), alpha inline, packed
  agg_kernel<<<dim3(NB_ND), dim3(256), 0, stream>>>(xb, rowptr, scol, nki, nkj, Pb);

  // GEMM1: Hb = relu(Pb @ W1 + b1)  [M=50176, K=512, N=1024]  grid 8 x 392
  gemm_kernel<true><<<dim3(H1 / 128, MPAD / 128), dim3(256), 0, stream>>>(
      Pb, W1t, b1, Hb, NNODES, D, H1);
  // GEMM2: out = Hb @ W2 + b2       [M=50176, K=1024, N=512]  grid 4 x 392
  gemm_kernel<false><<<dim3(D / 128, MPAD / 128), dim3(256), 0, stream>>>(
      Hb, W2t, b2, out, NNODES, H1, D);
}